// Round 13
// baseline (59.500 us; speedup 1.0000x reference)
//
#include <hip/hip_runtime.h>
#include <stdint.h>

#define N_ROWS 65536
#define K_CODES 1024
#define DIM 256

typedef unsigned int uint;

// d_ws layout:
//   [0, 4K)       loss accumulator (first 4B)
//   [4K, 8K)      enS[1024]: ||e||^2 * 32768 + 16384 (scaled+biased fp32)
//   [8K, +128K)   E4: fp4(e2m1) codebook scaled x4096, 128B per code
#define WS_LOSS_OFF  0
#define WS_ENS_OFF   4096
#define WS_E4_OFF    8192

typedef __attribute__((ext_vector_type(4))) float f32x4;
typedef __attribute__((ext_vector_type(4))) int   i32x4;
typedef __attribute__((ext_vector_type(8))) int   i32x8;

// X -> fp8 e4m3 scaled by -16 (negated so MFMA yields enS' - 2x.e directly)
#define XSCALE  (-16.0f)
#define ESCALE4 4096.0f
#define BIAS    16384.0f
#define UNSCALE 3.0517578125e-05f   // 1/32768, exact pow2
#define SCALE1  0x7F7F7F7Fu         // E8M0 identity scales

__device__ __forceinline__ uint pack4_fp8(float a, float b, float c, float d) {
    uint r = 0;
    r = __builtin_amdgcn_cvt_pk_fp8_f32(a, b, r, false);
    r = __builtin_amdgcn_cvt_pk_fp8_f32(c, d, r, true);
    return r;
}
// fp4 e2m1 encode: grid {0,0.5,1,1.5,2,3,4,6}, nearest; input |x|<=4 here
__device__ __forceinline__ uint enc_fp4(float x) {
    float a = fabsf(x);
    uint idx = (a < 0.25f) ? 0u : (a < 0.75f) ? 1u : (a < 1.25f) ? 2u :
               (a < 1.75f) ? 3u : (a < 2.5f)  ? 4u : (a < 3.5f)  ? 5u :
               (a < 5.0f)  ? 6u : 7u;
    return idx | ((x < 0.f) ? 8u : 0u);
}
__device__ __forceinline__ void gload_lds16(const void* g, void* l) {
    __builtin_amdgcn_global_load_lds(
        (const __attribute__((address_space(1))) void*)g,
        (__attribute__((address_space(3))) void*)l, 16, 0, 0);
}

// ---- prep: E -> fp4 codebook (x4096) + scaled/biased norms + zero loss -----
__global__ __launch_bounds__(256) void vq_prep(const float* __restrict__ E,
                                               unsigned char* __restrict__ E4,
                                               float* __restrict__ enS,
                                               float* __restrict__ lossAcc) {
    int id = blockIdx.x * 256 + threadIdx.x;      // 65536 = 1024 codes * 64 f4
    if (id == 0) lossAcc[0] = 0.f;
    int code = id >> 6, c4 = id & 63;
    float4 v = *reinterpret_cast<const float4*>(E + (size_t)code * DIM + c4 * 4);
    uint n0 = enc_fp4(v.x * ESCALE4), n1 = enc_fp4(v.y * ESCALE4);
    uint n2 = enc_fp4(v.z * ESCALE4), n3 = enc_fp4(v.w * ESCALE4);
    uint hw = (n0 | (n1 << 4)) | ((n2 | (n3 << 4)) << 8);
    *reinterpret_cast<unsigned short*>(E4 + (size_t)code * 128 + c4 * 2) =
        (unsigned short)hw;

    float s = v.x * v.x + v.y * v.y + v.z * v.z + v.w * v.w;
    #pragma unroll
    for (int m = 32; m >= 1; m >>= 1) s += __shfl_down(s, m, 64);
    if (c4 == 0) enS[code] = s * 32768.0f + BIAS;
}

// ---- fused main ------------------------------------------------------------
// Block: 128 thr = 2 waves, 64 rows (wave w: rows w*32..+31, m=2).
// Grid 1024 -> 4 independent blocks/CU (8 waves/CU): within-CU phase stagger.
// B: 8 tiles of 128 codes x 256 K fp4 (16KB), double-buffered, block-shared.
// Inner loop folds per n-PAIR: live acc = 16 VGPR (was 64) -> no spill.
// MFMA: A = fp8(-16x), B = fp4(4096e) blgp=4, C-init = enS' so
// acc_out = 32768*(||e||^2 - 2x.e) + 16384; u32-packed argmin fold.
__global__ __launch_bounds__(128, 2) void vq_main(const float* __restrict__ X,
                                                  const unsigned char* __restrict__ E4,
                                                  const float* __restrict__ enS,
                                                  const float* __restrict__ E,
                                                  float* __restrict__ out,
                                                  float* __restrict__ lossAcc) {
    __shared__ __align__(16) unsigned char bsm[2 * 16384];  // 2 x 128-code tiles
    __shared__ float enSLds[1024];
    __shared__ int   bcLds[64];
    __shared__ float lossSh;

    const int tid = threadIdx.x;
    const int lane = tid & 63;
    const int w = tid >> 6;          // wave 0/1
    const int cl = lane & 15;
    const int kq = lane >> 4;
    const int row0 = blockIdx.x * 64;
    const int key = (cl & 7) << 4;   // read-side XOR swizzle

    auto stageB = [&](int tile, int buf) {
        unsigned char* dst = bsm + buf * 16384;
        const unsigned char* src = E4 + (size_t)(tile * 128) * 128;
        #pragma unroll
        for (int j = 0; j < 8; ++j) {
            int o = j * 2048 + tid * 16;             // linear LDS dest
            int rr = o >> 7;                         // code row in tile (0..127)
            int cb = (o & 127) ^ ((rr & 7) << 4);    // pre-swizzled source (rule 21)
            gload_lds16(src + rr * 128 + cb, dst + o);
        }
    };

    stageB(0, 0);                    // issue first tile ASAP (oldest vmem)

    // enS -> LDS (1024 f32; two float4 per thread)
    #pragma unroll
    for (int i = 0; i < 2; ++i)
        reinterpret_cast<f32x4*>(enSLds)[i * 128 + tid] =
            reinterpret_cast<const f32x4*>(enS)[i * 128 + tid];
    if (tid == 0) lossSh = 0.f;

    // ---- A phase: global -> fp8(-x) regs (m=2, K=128 frags) + x^2 partial --
    i32x8 aF[2][2];
    float xsum = 0.f;
    #pragma unroll
    for (int m = 0; m < 2; ++m) {
        const float* rp = X + (size_t)(row0 + w * 32 + m * 16 + cl) * DIM;
        #pragma unroll
        for (int ks = 0; ks < 2; ++ks) {
            const float* p = rp + ks * 128 + kq * 32;
            uint u[8];
            #pragma unroll
            for (int q = 0; q < 8; ++q) {
                float4 v = *reinterpret_cast<const float4*>(p + q * 4);
                u[q] = pack4_fp8(v.x * XSCALE, v.y * XSCALE,
                                 v.z * XSCALE, v.w * XSCALE);
                xsum = fmaf(v.x, v.x, xsum); xsum = fmaf(v.y, v.y, xsum);
                xsum = fmaf(v.z, v.z, xsum); xsum = fmaf(v.w, v.w, xsum);
            }
            i32x8 f = {(int)u[0], (int)u[1], (int)u[2], (int)u[3],
                       (int)u[4], (int)u[5], (int)u[6], (int)u[7]};
            aF[m][ks] = f;
        }
    }

    uint best[2][4];
    #pragma unroll
    for (int m = 0; m < 2; ++m)
        #pragma unroll
        for (int rr = 0; rr < 4; ++rr) best[m][rr] = 0xFFFFFFFFu;

    for (int t = 0; t < 8; ++t) {
        __syncthreads();                 // stage(t) + (t==0: enSLds) visible
        if (t < 7) stageB(t + 1, (t + 1) & 1);   // writer -> other buffer

        const unsigned char* bb = bsm + (t & 1) * 16384;

        __builtin_amdgcn_s_setprio(1);
        #pragma unroll
        for (int np = 0; np < 4; ++np) {
            const int n0 = np * 2, n1 = np * 2 + 1;
            float en0 = enSLds[t * 128 + n0 * 16 + cl];
            float en1 = enSLds[t * 128 + n1 * 16 + cl];
            f32x4 a00 = {en0, en0, en0, en0};
            f32x4 a01 = {en1, en1, en1, en1};
            f32x4 a10 = a00, a11 = a01;
            const unsigned char* rb0 = bb + (size_t)(n0 * 16 + cl) * 128;
            const unsigned char* rb1 = bb + (size_t)(n1 * 16 + cl) * 128;
            #pragma unroll
            for (int ks = 0; ks < 2; ++ks) {
                int l0 = (ks * 64 + kq * 16) ^ key;
                i32x4 lo0 = *reinterpret_cast<const i32x4*>(rb0 + l0);
                i32x4 lo1 = *reinterpret_cast<const i32x4*>(rb1 + l0);
                i32x8 bf0 = __builtin_shufflevector(lo0, lo0, 0, 1, 2, 3, 0, 1, 2, 3);
                i32x8 bf1 = __builtin_shufflevector(lo1, lo1, 0, 1, 2, 3, 0, 1, 2, 3);
                a00 = __builtin_amdgcn_mfma_scale_f32_16x16x128_f8f6f4(
                    aF[0][ks], bf0, a00, 0, 4, 0, SCALE1, 0, SCALE1);
                a10 = __builtin_amdgcn_mfma_scale_f32_16x16x128_f8f6f4(
                    aF[1][ks], bf0, a10, 0, 4, 0, SCALE1, 0, SCALE1);
                a01 = __builtin_amdgcn_mfma_scale_f32_16x16x128_f8f6f4(
                    aF[0][ks], bf1, a01, 0, 4, 0, SCALE1, 0, SCALE1);
                a11 = __builtin_amdgcn_mfma_scale_f32_16x16x128_f8f6f4(
                    aF[1][ks], bf1, a11, 0, 4, 0, SCALE1, 0, SCALE1);
            }
            // u32-packed fold (codes ascend -> min keeps first occurrence)
            uint c0 = (uint)(t * 128 + n0 * 16 + cl);
            uint c1 = (uint)(t * 128 + n1 * 16 + cl);
            #pragma unroll
            for (int rr = 0; rr < 4; ++rr) {
                best[0][rr] = min(best[0][rr],
                                  (__float_as_uint(a00[rr]) & 0xFFFFFC00u) | c0);
                best[0][rr] = min(best[0][rr],
                                  (__float_as_uint(a01[rr]) & 0xFFFFFC00u) | c1);
                best[1][rr] = min(best[1][rr],
                                  (__float_as_uint(a10[rr]) & 0xFFFFFC00u) | c0);
                best[1][rr] = min(best[1][rr],
                                  (__float_as_uint(a11[rr]) & 0xFFFFFC00u) | c1);
            }
        }
        __builtin_amdgcn_s_setprio(0);
    }

    // ---- epilogue: cross-cl reduce; C-row = m*16 + kq*4 + rr (m89 layout) --
    float minsum = 0.f;
    #pragma unroll
    for (int m = 0; m < 2; ++m)
        #pragma unroll
        for (int rr = 0; rr < 4; ++rr) {
            uint v = best[m][rr];
            #pragma unroll
            for (int mask = 1; mask < 16; mask <<= 1)
                v = min(v, (uint)__shfl_xor((int)v, mask, 64));
            if (cl == 0) {
                int row_l = w * 32 + m * 16 + kq * 4 + rr;
                bcLds[row_l] = (int)(v & 1023u);
                minsum += __uint_as_float(v & 0xFFFFFC00u) - BIAS;
            }
        }
    // loss partial: every thread's x^2 + (cl==0 lanes') scaled min-scores
    float v2 = xsum + ((cl == 0) ? minsum * UNSCALE : 0.f);
    #pragma unroll
    for (int mask = 1; mask < 64; mask <<= 1) v2 += __shfl_xor(v2, mask, 64);
    if (lane == 0) atomicAdd(&lossSh, v2);
    __syncthreads();                          // bcLds + lossSh ready

    // ---- out[row] = E[bc[row]] (== x + (q-x) to ~3e-7), plain stores -------
    #pragma unroll 4
    for (int i = 0; i < 32; ++i) {
        int g = i * 128 + tid;                // 4096 f4 = 64 rows x 64
        int rr = g >> 6, c4 = g & 63;
        int code = bcLds[rr];
        f32x4 q = *reinterpret_cast<const f32x4*>(E + (size_t)code * DIM + c4 * 4);
        *reinterpret_cast<f32x4*>(out + (size_t)(row0 + rr) * DIM + c4 * 4) = q;
    }
    if (tid == 0) atomicAdd(lossAcc, lossSh);
}

__global__ void vq_finalize(const float* __restrict__ lossAcc,
                            float* __restrict__ out) {
    out[(size_t)N_ROWS * DIM] = 1.25f * lossAcc[0] / (float)((size_t)N_ROWS * DIM);
}

extern "C" void kernel_launch(void* const* d_in, const int* in_sizes, int n_in,
                              void* d_out, int out_size, void* d_ws, size_t ws_size,
                              hipStream_t stream) {
    const float* X = (const float*)d_in[0];
    const float* E = (const float*)d_in[1];
    float* out = (float*)d_out;

    char* ws = (char*)d_ws;
    float* lossAcc = (float*)(ws + WS_LOSS_OFF);
    float* enS = (float*)(ws + WS_ENS_OFF);
    unsigned char* E4 = (unsigned char*)(ws + WS_E4_OFF);

    vq_prep<<<256, 256, 0, stream>>>(E, E4, enS, lossAcc);
    vq_main<<<N_ROWS / 64, 128, 0, stream>>>(X, E4, enS, E, out, lossAcc);
    vq_finalize<<<1, 1, 0, stream>>>(lossAcc, out);
}

// Round 14
// 55.748 us; speedup vs baseline: 1.0673x; 1.0673x over previous
//
#include <hip/hip_runtime.h>
#include <stdint.h>

#define N_ROWS 65536
#define K_CODES 1024
#define DIM 256

typedef unsigned int uint;

// d_ws layout:
//   [0, 4K)       loss accumulator (first 4B)
//   [4K, 8K)      enS[1024]: ||e||^2 * 32768 + 16384 (scaled+biased fp32)
//   [8K, +128K)   E4: fp4(e2m1) codebook scaled x4096, 128B per code
#define WS_LOSS_OFF  0
#define WS_ENS_OFF   4096
#define WS_E4_OFF    8192

typedef __attribute__((ext_vector_type(4))) float f32x4;
typedef __attribute__((ext_vector_type(4))) int   i32x4;
typedef __attribute__((ext_vector_type(8))) int   i32x8;

// X -> fp8 e4m3 scaled by -16 (negated so MFMA yields enS' - 2x.e directly)
#define XSCALE  (-16.0f)
#define ESCALE4 4096.0f
#define BIAS    16384.0f
#define UNSCALE 3.0517578125e-05f   // 1/32768, exact pow2
#define SCALE1  0x7F7F7F7Fu         // E8M0 identity scales

__device__ __forceinline__ uint pack4_fp8(float a, float b, float c, float d) {
    uint r = 0;
    r = __builtin_amdgcn_cvt_pk_fp8_f32(a, b, r, false);
    r = __builtin_amdgcn_cvt_pk_fp8_f32(c, d, r, true);
    return r;
}
// fp4 e2m1 encode: grid {0,0.5,1,1.5,2,3,4,6}, nearest; input |x|<=4 here
__device__ __forceinline__ uint enc_fp4(float x) {
    float a = fabsf(x);
    uint idx = (a < 0.25f) ? 0u : (a < 0.75f) ? 1u : (a < 1.25f) ? 2u :
               (a < 1.75f) ? 3u : (a < 2.5f)  ? 4u : (a < 3.5f)  ? 5u :
               (a < 5.0f)  ? 6u : 7u;
    return idx | ((x < 0.f) ? 8u : 0u);
}
__device__ __forceinline__ void gload_lds16(const void* g, void* l) {
    __builtin_amdgcn_global_load_lds(
        (const __attribute__((address_space(1))) void*)g,
        (__attribute__((address_space(3))) void*)l, 16, 0, 0);
}

// ---- prep: E -> fp4 codebook (x4096) + scaled/biased norms + zero loss -----
__global__ __launch_bounds__(256) void vq_prep(const float* __restrict__ E,
                                               unsigned char* __restrict__ E4,
                                               float* __restrict__ enS,
                                               float* __restrict__ lossAcc) {
    int id = blockIdx.x * 256 + threadIdx.x;      // 65536 = 1024 codes * 64 f4
    if (id == 0) lossAcc[0] = 0.f;
    int code = id >> 6, c4 = id & 63;
    float4 v = *reinterpret_cast<const float4*>(E + (size_t)code * DIM + c4 * 4);
    uint n0 = enc_fp4(v.x * ESCALE4), n1 = enc_fp4(v.y * ESCALE4);
    uint n2 = enc_fp4(v.z * ESCALE4), n3 = enc_fp4(v.w * ESCALE4);
    uint hw = (n0 | (n1 << 4)) | ((n2 | (n3 << 4)) << 8);
    *reinterpret_cast<unsigned short*>(E4 + (size_t)code * 128 + c4 * 2) =
        (unsigned short)hw;

    float s = v.x * v.x + v.y * v.y + v.z * v.z + v.w * v.w;
    #pragma unroll
    for (int m = 32; m >= 1; m >>= 1) s += __shfl_down(s, m, 64);
    if (c4 == 0) enS[code] = s * 32768.0f + BIAS;
}

// ---- fused main ------------------------------------------------------------
// TWO-GENERATION schedule: grid 1024 blocks of 256 thr (4 waves, 64 rows,
// m=1: wave w owns rows w*16..+15). LDS deliberately ~53.5KB so only 2
// blocks/CU are resident -> 1024/(2*256) = 2 generations; gen-2 A-phases
// overlap gen-1 loops/out-phases (burst de-synchronization).
// B: 8 tiles of 128 codes x 256 K fp4 (16KB), double-buffered, block-shared.
// MFMA: A = fp8(-16x), B = fp4(4096e) blgp=4, C-init = enS' so
// acc_out = 32768*(||e||^2 - 2x.e) + 16384; u32-packed argmin fold.
// __launch_bounds__(256,1): relax VGPR cap (no 128-reg spill).
__global__ __launch_bounds__(256, 1) void vq_main(const float* __restrict__ X,
                                                  const unsigned char* __restrict__ E4,
                                                  const float* __restrict__ enS,
                                                  const float* __restrict__ E,
                                                  float* __restrict__ out,
                                                  float* __restrict__ lossAcc) {
    // 2 x 24576 arena (16384 used per buffer; padding caps residency at 2/CU)
    __shared__ __align__(16) unsigned char bsm[2 * 24576];
    __shared__ float enSLds[1024];
    __shared__ int   bcLds[64];
    __shared__ float lossSh;

    const int tid = threadIdx.x;
    const int lane = tid & 63;
    const int w = tid >> 6;          // wave 0..3
    const int cl = lane & 15;
    const int kq = lane >> 4;
    const int row0 = blockIdx.x * 64;
    const int key = (cl & 7) << 4;   // read-side XOR swizzle

    auto stageB = [&](int tile, int buf) {
        unsigned char* dst = bsm + buf * 24576;
        const unsigned char* src = E4 + (size_t)(tile * 128) * 128;
        #pragma unroll
        for (int j = 0; j < 4; ++j) {
            int o = j * 4096 + tid * 16;             // linear LDS dest
            int rr = o >> 7;                         // code row in tile (0..127)
            int cb = (o & 127) ^ ((rr & 7) << 4);    // pre-swizzled source (rule 21)
            gload_lds16(src + rr * 128 + cb, dst + o);
        }
    };

    stageB(0, 0);                    // issue first tile ASAP (oldest vmem)

    // enS -> LDS (1024 f32; one float4 per thread)
    reinterpret_cast<f32x4*>(enSLds)[tid] =
        reinterpret_cast<const f32x4*>(enS)[tid];
    if (tid == 0) lossSh = 0.f;

    // ---- A phase: global -> fp8(-x) regs (m=1, K=128 frags) + x^2 partial --
    i32x8 aF[2];
    float xsum = 0.f;
    {
        const float* rp = X + (size_t)(row0 + w * 16 + cl) * DIM;
        #pragma unroll
        for (int ks = 0; ks < 2; ++ks) {
            const float* p = rp + ks * 128 + kq * 32;
            uint u[8];
            #pragma unroll
            for (int q = 0; q < 8; ++q) {
                float4 v = *reinterpret_cast<const float4*>(p + q * 4);
                u[q] = pack4_fp8(v.x * XSCALE, v.y * XSCALE,
                                 v.z * XSCALE, v.w * XSCALE);
                xsum = fmaf(v.x, v.x, xsum); xsum = fmaf(v.y, v.y, xsum);
                xsum = fmaf(v.z, v.z, xsum); xsum = fmaf(v.w, v.w, xsum);
            }
            i32x8 f = {(int)u[0], (int)u[1], (int)u[2], (int)u[3],
                       (int)u[4], (int)u[5], (int)u[6], (int)u[7]};
            aF[ks] = f;
        }
    }

    uint best[4];
    #pragma unroll
    for (int rr = 0; rr < 4; ++rr) best[rr] = 0xFFFFFFFFu;

    for (int t = 0; t < 8; ++t) {
        __syncthreads();                 // stage(t) + (t==0: enSLds) visible
        if (t < 7) stageB(t + 1, (t + 1) & 1);   // writer -> other buffer

        const unsigned char* bb = bsm + (t & 1) * 24576;

        __builtin_amdgcn_s_setprio(1);
        #pragma unroll
        for (int n = 0; n < 8; ++n) {
            float en = enSLds[t * 128 + n * 16 + cl];
            f32x4 acc = {en, en, en, en};
            const unsigned char* rb = bb + (size_t)(n * 16 + cl) * 128;
            #pragma unroll
            for (int ks = 0; ks < 2; ++ks) {
                i32x4 lo = *reinterpret_cast<const i32x4*>(
                    rb + ((ks * 64 + kq * 16) ^ key));
                i32x8 bf = __builtin_shufflevector(lo, lo, 0, 1, 2, 3, 0, 1, 2, 3);
                acc = __builtin_amdgcn_mfma_scale_f32_16x16x128_f8f6f4(
                    aF[ks], bf, acc, 0, 4, 0, SCALE1, 0, SCALE1);
            }
            // u32-packed fold (codes ascend -> min keeps first occurrence)
            uint codeN = (uint)(t * 128 + n * 16 + cl);
            #pragma unroll
            for (int rr = 0; rr < 4; ++rr) {
                uint pk = (__float_as_uint(acc[rr]) & 0xFFFFFC00u) | codeN;
                best[rr] = min(best[rr], pk);
            }
        }
        __builtin_amdgcn_s_setprio(0);
    }

    // ---- epilogue: cross-cl reduce; C-row = kq*4 + rr (m89 layout, m=1) ----
    float minsum = 0.f;
    #pragma unroll
    for (int rr = 0; rr < 4; ++rr) {
        uint v = best[rr];
        #pragma unroll
        for (int mask = 1; mask < 16; mask <<= 1)
            v = min(v, (uint)__shfl_xor((int)v, mask, 64));
        if (cl == 0) {
            int row_l = w * 16 + kq * 4 + rr;
            bcLds[row_l] = (int)(v & 1023u);
            minsum += __uint_as_float(v & 0xFFFFFC00u) - BIAS;
        }
    }
    // loss partial: every thread's x^2 + (cl==0 lanes') scaled min-scores
    float v2 = xsum + ((cl == 0) ? minsum * UNSCALE : 0.f);
    #pragma unroll
    for (int mask = 1; mask < 64; mask <<= 1) v2 += __shfl_xor(v2, mask, 64);
    if (lane == 0) atomicAdd(&lossSh, v2);
    __syncthreads();                          // bcLds + lossSh ready

    // ---- out[row] = E[bc[row]] (== x + (q-x) to ~3e-7) ---------------------
    #pragma unroll 4
    for (int i = 0; i < 16; ++i) {
        int g = i * 256 + tid;                // 4096 f4 = 64 rows x 64
        int rr = g >> 6, c4 = g & 63;
        int code = bcLds[rr];
        f32x4 q = *reinterpret_cast<const f32x4*>(E + (size_t)code * DIM + c4 * 4);
        *reinterpret_cast<f32x4*>(out + (size_t)(row0 + rr) * DIM + c4 * 4) = q;
    }
    if (tid == 0) atomicAdd(lossAcc, lossSh);
}

__global__ void vq_finalize(const float* __restrict__ lossAcc,
                            float* __restrict__ out) {
    out[(size_t)N_ROWS * DIM] = 1.25f * lossAcc[0] / (float)((size_t)N_ROWS * DIM);
}

extern "C" void kernel_launch(void* const* d_in, const int* in_sizes, int n_in,
                              void* d_out, int out_size, void* d_ws, size_t ws_size,
                              hipStream_t stream) {
    const float* X = (const float*)d_in[0];
    const float* E = (const float*)d_in[1];
    float* out = (float*)d_out;

    char* ws = (char*)d_ws;
    float* lossAcc = (float*)(ws + WS_LOSS_OFF);
    float* enS = (float*)(ws + WS_ENS_OFF);
    unsigned char* E4 = (unsigned char*)(ws + WS_E4_OFF);

    vq_prep<<<256, 256, 0, stream>>>(E, E4, enS, lossAcc);
    vq_main<<<N_ROWS / 64, 256, 0, stream>>>(X, E4, enS, E, out, lossAcc);
    vq_finalize<<<1, 1, 0, stream>>>(lossAcc, out);
}